// Round 16
// baseline (76.191 us; speedup 1.0000x reference)
//
#include <hip/hip_runtime.h>
#include <math.h>

namespace {
constexpr int B = 4, N = 4, C = 64, H = 128, W = 256, L = 5;
constexpr int HW = H * W;
constexpr int WAVES = 8;          // waves per block
constexpr int CPW = 4;            // channels per wave (8 waves x 4 = 32 = C/2)
constexpr int NXCD = 8;
constexpr int NWG = B * (W / 64) * H * 2;   // 4096 (x2 channel-halves), %8==0
}

// 8-byte pair load with only 4-byte alignment guarantee (x-taps are adjacent).
typedef float f2v __attribute__((ext_vector_type(2), aligned(4)));

__global__ __launch_bounds__(512, 4) void atten_comm_kernel(
    const float* __restrict__ x,    // (B*N, C, H, W)
    const float* __restrict__ P,    // (B, L, L, 4, 4)
    float* __restrict__ out)        // (B, C, H, W)
{
    __shared__ float sred[WAVES][N][64];

    // XCD-aware swizzle (T1): each XCD gets 512 consecutive orig ids.
    // orig bit layout: [0]=chalf, [1:7]=h, [8:9]=wc, [10:11]=b  (chalf
    // fastest: both channel-halves of a tile read the same warped rows).
    const int g     = (int)blockIdx.x;
    const int orig  = (g & (NXCD - 1)) * (NWG / NXCD) + (g >> 3);
    const int chalf = orig & 1;
    const int h     = (orig >> 1) & (H - 1);
    const int wc    = (orig >> 8) & 3;
    const int b     = orig >> 10;

    const int lane = (int)(threadIdx.x & 63);
    const int wv   = (int)(threadIdx.x >> 6);
    const int w    = (wc << 6) + lane;
    const int cbase = chalf * (C / 2) + wv * CPW;   // this wave's channels

    // normalized grid coords (align_corners=True)
    const float gx = -1.0f + (2.0f / (float)(W - 1)) * (float)w;
    const float gy = -1.0f + (2.0f / (float)(H - 1)) * (float)h;

    const float* basep[N];
    int   voff0[N], voff1[N];               // element offsets of the two row pairs
    float u0x[N], u0y[N], u1x[N], u1y[N];   // folded bilinear+boundary weights

#pragma unroll
    for (int n = 0; n < N; ++n) {
        // P[b, 0, n, r, c]; strides: b:L*L*16, i:L*16, j:16, r:4, c:1
        const float* p = P + ((size_t)b * L * L + (size_t)n) * 16;
        const float a  = p[0];
        const float bb = p[1] * ((float)H / (float)W);
        const float cc = p[3] * (2.0f / (4.0f * 0.4f * (float)W));
        const float d  = p[4] * ((float)W / (float)H);
        const float e  = p[5];
        const float ff = p[7] * (2.0f / (4.0f * 0.4f * (float)H));

        const float g0 = a * gx + bb * gy + cc;
        const float g1 = d * gx + e * gy + ff;
        const float ix = (g0 + 1.0f) * (0.5f * (float)(W - 1));
        const float iy = (g1 + 1.0f) * (0.5f * (float)(H - 1));

        const float fx0 = floorf(ix);
        const float fy0 = floorf(iy);
        const int x0 = (int)fx0, y0 = (int)fy0;
        const int y1 = y0 + 1;
        const float wx = ix - fx0;
        const float wy = iy - fy0;

        // x-pair: load (xa, xa+1); both x-taps live in this window with
        // boundary cases folded into (ux, uy):
        const int   xa   = min(max(x0, 0), W - 2);
        const float wx0v = (1.0f - wx) * ((x0 >= 0 && x0 < W) ? 1.0f : 0.0f);
        const float wx1v = wx * ((x0 + 1 >= 0 && x0 + 1 < W) ? 1.0f : 0.0f);
        // interior: (wx0v, wx1v); x0==-1: taps shift left -> (wx1v, 0);
        // x0==W-1: taps shift right -> (0, wx0v); fully OOB collapses to 0.
        const float ux = (x0 < 0) ? wx1v : ((x0 > W - 2) ? 0.0f : wx0v);
        const float uy = (x0 < 0) ? 0.0f : ((x0 > W - 2) ? wx0v : wx1v);

        const int yc0 = min(max(y0, 0), H - 1);
        const int yc1 = min(max(y1, 0), H - 1);
        const float wyv0 = (1.0f - wy) * ((y0 >= 0 && y0 < H) ? 1.0f : 0.0f);
        const float wyv1 = wy * ((y1 >= 0 && y1 < H) ? 1.0f : 0.0f);

        u0x[n] = ux * wyv0;  u0y[n] = uy * wyv0;
        u1x[n] = ux * wyv1;  u1y[n] = uy * wyv1;
        voff0[n] = yc0 * W + xa;
        voff1[n] = yc1 * W + xa;

        basep[n] = x + ((size_t)(b * N + n) * C + (size_t)cbase) * HW;
    }

    // ---- gather: 8 pair-loads per channel issued before the FMAs ----
    float f[N][CPW];
#pragma unroll
    for (int cc = 0; cc < CPW; ++cc) {
        f2v t0[N], t1[N];
#pragma unroll
        for (int n = 0; n < N; ++n) {
            const float* pl = basep[n] + (size_t)cc * HW;
            t0[n] = *(const f2v*)(pl + voff0[n]);
            t1[n] = *(const f2v*)(pl + voff1[n]);
        }
#pragma unroll
        for (int n = 0; n < N; ++n) {
            f[n][cc] = u0x[n] * t0[n].x + u0y[n] * t0[n].y
                     + u1x[n] * t1[n].x + u1y[n] * t1[n].y;
        }
    }

    // ---- partial scores over this wave's channels ----
    float s[N] = {0.f, 0.f, 0.f, 0.f};
#pragma unroll
    for (int cc = 0; cc < CPW; ++cc) {
        const float q = f[0][cc];
#pragma unroll
        for (int n = 0; n < N; ++n) s[n] += q * f[n][cc];
    }

    // ---- cross-wave reduction via LDS (half-score; other half is in the
    // sibling block). Scores need ALL C channels: reduce this block's 32,
    // then combine with the sibling's via global atomics? No -- instead
    // each block computes the full score itself: channels are split
    // 32/32 between the two sibling blocks, so we must re-derive the
    // other half. Cheaper: both siblings compute the same full score by
    // having every wave ALSO dot the sibling half? That doubles loads.
    // Resolution: score uses only q0 = f[0] which needs all 64 channels.
    // We avoid cross-block traffic by reducing over the 8 waves (32 ch)
    // and correcting with the identity that softmax over n is invariant
    // to which block computed it -- NOT valid. So: both chalf blocks
    // gather the same data? No. We instead compute the score over all 64
    // channels IN EACH SIBLING by splitting differently: each wave loads
    // its 4 channels of BOTH halves only for the score q0*f dot?
    // -- Simplest correct scheme kept below: the 8 waves of this block
    // cover 32 channels; sibling covers the other 32. Each block writes
    // its half-score to its own LDS and reads the sibling's half from
    // global scratch would break graph rules. Therefore: waves here
    // compute BOTH their context channels (4) and score-contribution
    // for 8 channels (their 4 + sibling's mirrored 4) would re-load.
    // => Fall back to the proven full-C-per-block score: each wave's
    // score partial covers its 4 ctx channels plus the mirrored-half
    // channel set via 4 extra gathers ONLY for the dot products.
    // ---- (see score_extra below) ----
#pragma unroll
    for (int n = 0; n < N; ++n) sred[wv][n][lane] = s[n];

    // extra score contribution: the sibling half's corresponding channels
    // (cbase ^ 32). 8 waves x 4 ch = the full other half. Only the dot
    // products need these values, not the context.
    {
        const int sbase = cbase ^ (C / 2);
        float s2[N] = {0.f, 0.f, 0.f, 0.f};
#pragma unroll
        for (int cc = 0; cc < CPW; ++cc) {
            f2v t0[N], t1[N];
#pragma unroll
            for (int n = 0; n < N; ++n) {
                const float* pl = basep[n] + ((size_t)(sbase - cbase) + (size_t)cc) * HW;
                t0[n] = *(const f2v*)(pl + voff0[n]);
                t1[n] = *(const f2v*)(pl + voff1[n]);
            }
            float fv[N];
#pragma unroll
            for (int n = 0; n < N; ++n) {
                fv[n] = u0x[n] * t0[n].x + u0y[n] * t0[n].y
                      + u1x[n] * t1[n].x + u1y[n] * t1[n].y;
            }
            const float q = fv[0];
#pragma unroll
            for (int n = 0; n < N; ++n) s2[n] += q * fv[n];
        }
        __syncthreads();   // sred writes visible
#pragma unroll
        for (int n = 0; n < N; ++n) {
            // accumulate sibling-half partials into LDS (one writer per
            // [wv][n][lane] slot: this wave) -- no race.
            sred[wv][n][lane] += s2[n];
        }
    }
    __syncthreads();

    float st[N];
#pragma unroll
    for (int n = 0; n < N; ++n) {
        float acc = 0.f;
#pragma unroll
        for (int v = 0; v < WAVES; ++v) acc += sred[v][n][lane];
        st[n] = acc;
    }

    const float scale = 0.125f;  // 1/sqrt(64)
    const float s0 = st[0] * scale, s1 = st[1] * scale;
    const float s2 = st[2] * scale, s3 = st[3] * scale;
    const float m  = fmaxf(fmaxf(s0, s1), fmaxf(s2, s3));
    const float e0 = expf(s0 - m);
    const float e1 = expf(s1 - m);
    const float e2 = expf(s2 - m);
    const float e3 = expf(s3 - m);
    const float inv = 1.0f / (e0 + e1 + e2 + e3);
    const float attn[N] = {e0 * inv, e1 * inv, e2 * inv, e3 * inv};

    // ---- context from registers + coalesced store ----
    float* op = out + ((size_t)b * C + (size_t)cbase) * HW
                    + (size_t)h * W + (size_t)w;
#pragma unroll
    for (int cc = 0; cc < CPW; ++cc) {
        float ctx = 0.f;
#pragma unroll
        for (int n = 0; n < N; ++n) ctx += attn[n] * f[n][cc];
        op[(size_t)cc * HW] = ctx;
    }
}

extern "C" void kernel_launch(void* const* d_in, const int* in_sizes, int n_in,
                              void* d_out, int out_size, void* d_ws, size_t ws_size,
                              hipStream_t stream) {
    const float* x  = (const float*)d_in[0];
    const float* P  = (const float*)d_in[1];
    float* out = (float*)d_out;

    dim3 block(512, 1, 1);
    dim3 grid(NWG, 1, 1);  // 4096 blocks, 1D, XCD-swizzled in-kernel
    hipLaunchKernelGGL(atten_comm_kernel, grid, block, 0, stream, x, P, out);
}

// Round 17
// 45.589 us; speedup vs baseline: 1.6713x; 1.6713x over previous
//
#include <hip/hip_runtime.h>
#include <math.h>

namespace {
constexpr int B = 4, N = 4, C = 64, H = 128, W = 256, L = 5;
constexpr int HW = H * W;
constexpr int WAVES = 8;          // waves per block
constexpr int CPW = C / WAVES;    // channels per wave = 8
constexpr int NXCD = 8;
constexpr int NWG = B * (W / 64) * H;   // 2048, divisible by 8
}

// 8-byte pair load with only 4-byte alignment guarantee (x-taps are adjacent).
typedef float f2v __attribute__((ext_vector_type(2), aligned(4)));

__global__ __launch_bounds__(512, 4) void atten_comm_kernel(
    const float* __restrict__ x,    // (B*N, C, H, W)
    const float* __restrict__ P,    // (B, L, L, 4, 4)
    float* __restrict__ out)        // (B, C, H, W)
{
    __shared__ float sred[WAVES][N][64];

    // XCD-aware swizzle (T1): dispatch round-robins wg->XCD by (g % 8).
    // Give each XCD a contiguous orig-id chunk so consecutive-h blocks
    // (which share warped source rows) co-reside in one XCD's L2.
    const int g    = (int)blockIdx.x;
    const int orig = (g & (NXCD - 1)) * (NWG / NXCD) + (g >> 3);
    const int h    = orig & (H - 1);          // h fastest
    const int wc   = (orig >> 7) & 3;         // then w-chunk
    const int b    = orig >> 9;               // then batch

    const int lane = (int)(threadIdx.x & 63);
    const int wv   = (int)(threadIdx.x >> 6);
    const int w    = (wc << 6) + lane;

    // normalized grid coords (align_corners=True)
    const float gx = -1.0f + (2.0f / (float)(W - 1)) * (float)w;
    const float gy = -1.0f + (2.0f / (float)(H - 1)) * (float)h;

    const float* basep[N];
    int   voff0[N], voff1[N];               // element offsets of the two row pairs
    float u0x[N], u0y[N], u1x[N], u1y[N];   // folded bilinear+boundary weights

#pragma unroll
    for (int n = 0; n < N; ++n) {
        // P[b, 0, n, r, c]; strides: b:L*L*16, i:L*16, j:16, r:4, c:1
        const float* p = P + ((size_t)b * L * L + (size_t)n) * 16;
        const float a  = p[0];
        const float bb = p[1] * ((float)H / (float)W);
        const float cc = p[3] * (2.0f / (4.0f * 0.4f * (float)W));
        const float d  = p[4] * ((float)W / (float)H);
        const float e  = p[5];
        const float ff = p[7] * (2.0f / (4.0f * 0.4f * (float)H));

        const float g0 = a * gx + bb * gy + cc;
        const float g1 = d * gx + e * gy + ff;
        const float ix = (g0 + 1.0f) * (0.5f * (float)(W - 1));
        const float iy = (g1 + 1.0f) * (0.5f * (float)(H - 1));

        const float fx0 = floorf(ix);
        const float fy0 = floorf(iy);
        const int x0 = (int)fx0, y0 = (int)fy0;
        const int y1 = y0 + 1;
        const float wx = ix - fx0;
        const float wy = iy - fy0;

        // x-pair: load (xa, xa+1); both x-taps live in this window with
        // boundary cases folded into (ux, uy):
        const int   xa   = min(max(x0, 0), W - 2);
        const float wx0v = (1.0f - wx) * ((x0 >= 0 && x0 < W) ? 1.0f : 0.0f);
        const float wx1v = wx * ((x0 + 1 >= 0 && x0 + 1 < W) ? 1.0f : 0.0f);
        // interior: (wx0v, wx1v); x0==-1: taps shift left -> (wx1v, 0);
        // x0==W-1: taps shift right -> (0, wx0v); fully OOB collapses to 0.
        const float ux = (x0 < 0) ? wx1v : ((x0 > W - 2) ? 0.0f : wx0v);
        const float uy = (x0 < 0) ? 0.0f : ((x0 > W - 2) ? wx0v : wx1v);

        const int yc0 = min(max(y0, 0), H - 1);
        const int yc1 = min(max(y1, 0), H - 1);
        const float wyv0 = (1.0f - wy) * ((y0 >= 0 && y0 < H) ? 1.0f : 0.0f);
        const float wyv1 = wy * ((y1 >= 0 && y1 < H) ? 1.0f : 0.0f);

        u0x[n] = ux * wyv0;  u0y[n] = uy * wyv0;
        u1x[n] = ux * wyv1;  u1y[n] = uy * wyv1;
        voff0[n] = yc0 * W + xa;
        voff1[n] = yc1 * W + xa;

        basep[n] = x + ((size_t)(b * N + n) * C + (size_t)(wv * CPW)) * HW;
    }

    // ---- gather: 8 pair-loads per channel issued before the FMAs ----
    float f[N][CPW];
#pragma unroll
    for (int cc = 0; cc < CPW; ++cc) {
        f2v t0[N], t1[N];
#pragma unroll
        for (int n = 0; n < N; ++n) {
            const float* pl = basep[n] + (size_t)cc * HW;
            t0[n] = *(const f2v*)(pl + voff0[n]);
            t1[n] = *(const f2v*)(pl + voff1[n]);
        }
#pragma unroll
        for (int n = 0; n < N; ++n) {
            f[n][cc] = u0x[n] * t0[n].x + u0y[n] * t0[n].y
                     + u1x[n] * t1[n].x + u1y[n] * t1[n].y;
        }
    }

    // ---- partial scores over this wave's channels ----
    float s[N] = {0.f, 0.f, 0.f, 0.f};
#pragma unroll
    for (int cc = 0; cc < CPW; ++cc) {
        const float q = f[0][cc];
#pragma unroll
        for (int n = 0; n < N; ++n) s[n] += q * f[n][cc];
    }

    // ---- cross-wave reduction via LDS (lane-stride-1, conflict-free) ----
#pragma unroll
    for (int n = 0; n < N; ++n) sred[wv][n][lane] = s[n];
    __syncthreads();

    float st[N];
#pragma unroll
    for (int n = 0; n < N; ++n) {
        float acc = 0.f;
#pragma unroll
        for (int v = 0; v < WAVES; ++v) acc += sred[v][n][lane];
        st[n] = acc;
    }

    const float scale = 0.125f;  // 1/sqrt(64)
    const float s0 = st[0] * scale, s1 = st[1] * scale;
    const float s2 = st[2] * scale, s3 = st[3] * scale;
    const float m  = fmaxf(fmaxf(s0, s1), fmaxf(s2, s3));
    const float e0 = expf(s0 - m);
    const float e1 = expf(s1 - m);
    const float e2 = expf(s2 - m);
    const float e3 = expf(s3 - m);
    const float inv = 1.0f / (e0 + e1 + e2 + e3);
    const float attn[N] = {e0 * inv, e1 * inv, e2 * inv, e3 * inv};

    // ---- context from registers + coalesced store ----
    float* op = out + ((size_t)b * C + (size_t)(wv * CPW)) * HW
                    + (size_t)h * W + (size_t)w;
#pragma unroll
    for (int cc = 0; cc < CPW; ++cc) {
        float ctx = 0.f;
#pragma unroll
        for (int n = 0; n < N; ++n) ctx += attn[n] * f[n][cc];
        op[(size_t)cc * HW] = ctx;
    }
}

extern "C" void kernel_launch(void* const* d_in, const int* in_sizes, int n_in,
                              void* d_out, int out_size, void* d_ws, size_t ws_size,
                              hipStream_t stream) {
    const float* x  = (const float*)d_in[0];
    const float* P  = (const float*)d_in[1];
    float* out = (float*)d_out;

    dim3 block(512, 1, 1);
    dim3 grid(NWG, 1, 1);  // 2048 blocks, 1D, XCD-swizzled in-kernel
    hipLaunchKernelGGL(atten_comm_kernel, grid, block, 0, stream, x, P, out);
}